// Round 2
// baseline (176.320 us; speedup 1.0000x reference)
//
#include <hip/hip_runtime.h>
#include <hip/hip_bf16.h>

typedef __attribute__((ext_vector_type(8))) short bf16x8;
typedef __attribute__((ext_vector_type(4))) float f32x4;
typedef unsigned int u32;
typedef unsigned short u16;

#define NPOS 147456      // 384*384
#define NTILES 9216      // NPOS/16

__device__ inline u16 bfc(float f) {
  union { __hip_bfloat16 h; u16 s; } u;
  u.h = __float2bfloat16(f);
  return u.s;
}

// ---------------------------------------------------------------------------
// Prologue: bake bf16 weight fragments into ws, in exact MFMA lane layout.
// ws layout in u16 units:
//   wqf [0,8192)      : 16 frags (n*4+kc), frag = 64 lanes x 8 elems, Wq^T*0.25
//   wkf [8192,12288)  :  8 frags (n*2+kc), Wk^T
//   wvf [12288,16384) :  8 frags (n*2+kc), Wv^T
//   wof [16384,24576) : 16 frags (n8*2+kc), Wo^T
// Frag elem (lane,e): A[row=lane&15][k=(lane>>4)*8+e] of the 16x32 operand.
// ---------------------------------------------------------------------------
__global__ void prep_kernel(const float* __restrict__ wq, const float* __restrict__ wk,
                            const float* __restrict__ wv, const float* __restrict__ wo,
                            u16* __restrict__ wsf) {
  int gid = blockIdx.x * 256 + threadIdx.x;   // [0, 24576)
  int idx, which;
  if (gid < 8192)       { idx = gid;         which = 0; }
  else if (gid < 12288) { idx = gid - 8192;  which = 1; }
  else if (gid < 16384) { idx = gid - 12288; which = 2; }
  else                  { idx = gid - 16384; which = 3; }
  int fragid = idx >> 9, lane = (idx >> 3) & 63, e = idx & 7;
  int l15 = lane & 15, g = lane >> 4;
  float v;
  if (which == 0) {        // wq: [4][128][16], A[row=d][k=c]
    int n = fragid >> 2, kc = fragid & 3;
    int c = kc * 32 + g * 8 + e;
    v = wq[n * 2048 + c * 16 + l15] * 0.25f;   // fold D^-0.5
  } else if (which == 1) { // wk: [4][64][16], A[row=d][k=c]
    int n = fragid >> 1, kc = fragid & 1;
    int c = kc * 32 + g * 8 + e;
    v = wk[n * 1024 + c * 16 + l15];
  } else if (which == 2) { // wv
    int n = fragid >> 1, kc = fragid & 1;
    int c = kc * 32 + g * 8 + e;
    v = wv[n * 1024 + c * 16 + l15];
  } else {                 // wo: [4][16][128], A[row=cq-sub][k=hd]
    int n8 = fragid >> 1, kc = fragid & 1;
    int hd = kc * 32 + g * 8 + e;
    v = wo[(hd >> 4) * 2048 + (hd & 15) * 128 + n8 * 16 + l15];
  }
  wsf[gid] = bfc(v);
}

// frag-unit (bf16x8) index bases in ws
#define WQF(n, kc)  ((      (n) * 4 + (kc)) * 64)
#define WKF(n, kc)  (1024 + ((n) * 2 + (kc)) * 64)
#define WVF(n, kc)  (1536 + ((n) * 2 + (kc)) * 64)
#define WOF(n8, kc) (2048 + ((n8) * 2 + (kc)) * 64)

// ---------------------------------------------------------------------------
// Main: 1 wave per 16-position tile. No LDS, no __syncthreads.
// ---------------------------------------------------------------------------
__global__ __launch_bounds__(64, 4) void tpa_kernel(
    const float* __restrict__ qe, const float* __restrict__ tpr,
    const float* __restrict__ tmk_p, const float* __restrict__ ob,
    const u16* __restrict__ wsf, float* __restrict__ out)
{
  const int lane = threadIdx.x;
  const int l15 = lane & 15, g = lane >> 4;
  const int p0 = blockIdx.x * 16;
  const bf16x8* __restrict__ wf = reinterpret_cast<const bf16x8*>(wsf);

  const float m0 = tmk_p[0], m1 = tmk_p[1], m2 = tmk_p[2], m3 = tmk_p[3];
  const float biasv[4] = {65504.0f * (m0 - 1.0f), 65504.0f * (m1 - 1.0f),
                          65504.0f * (m2 - 1.0f), 65504.0f * (m3 - 1.0f)};
  const float tmk = (m0 + m1 + m2 + m3 > 0.0f) ? 1.0f : 0.0f;

  // ---- issue q loads + first two template rows ----
  const f32x4* qbase = reinterpret_cast<const f32x4*>(qe) + (p0 + l15) * 32 + g * 2;
  f32x4 qv[8];
  #pragma unroll
  for (int kc = 0; kc < 4; ++kc) {
    qv[kc * 2 + 0] = qbase[kc * 8 + 0];
    qv[kc * 2 + 1] = qbase[kc * 8 + 1];
  }
  f32x4 tv[4][4];
  #pragma unroll
  for (int t = 0; t < 2; ++t) {
    const f32x4* tbase = reinterpret_cast<const f32x4*>(tpr) +
                         ((size_t)t * NPOS + p0 + l15) * 16 + g * 2;
    #pragma unroll
    for (int kc = 0; kc < 2; ++kc) {
      tv[t][kc * 2 + 0] = tbase[kc * 8 + 0];
      tv[t][kc * 2 + 1] = tbase[kc * 8 + 1];
    }
  }

  // ---- GEMM1 (swapped): qT[n] = Q^T tile, lane = [d=g*4+r][pos=l15] ----
  f32x4 qT[4];
  #pragma unroll
  for (int n = 0; n < 4; ++n) qT[n] = (f32x4){0.f, 0.f, 0.f, 0.f};
  #pragma unroll
  for (int kc = 0; kc < 4; ++kc) {
    bf16x8 aq;
    #pragma unroll
    for (int e = 0; e < 8; ++e)
      aq[e] = (short)bfc(e < 4 ? qv[kc * 2 + 0][e] : qv[kc * 2 + 1][e - 4]);
    #pragma unroll
    for (int n = 0; n < 4; ++n)
      qT[n] = __builtin_amdgcn_mfma_f32_16x16x32_bf16(wf[WQF(n, kc) + lane], aq, qT[n], 0, 0, 0);
  }

  // ---- template loop: K/V proj + no-max softmax accumulate ----
  float ssum[4] = {0.f, 0.f, 0.f, 0.f};
  f32x4 wvT[4];
  #pragma unroll
  for (int n = 0; n < 4; ++n) wvT[n] = (f32x4){0.f, 0.f, 0.f, 0.f};

  #pragma unroll
  for (int t = 0; t < 4; ++t) {
    if (t < 2) {  // prefetch template t+2
      const f32x4* tbase = reinterpret_cast<const f32x4*>(tpr) +
                           ((size_t)(t + 2) * NPOS + p0 + l15) * 16 + g * 2;
      #pragma unroll
      for (int kc = 0; kc < 2; ++kc) {
        tv[t + 2][kc * 2 + 0] = tbase[kc * 8 + 0];
        tv[t + 2][kc * 2 + 1] = tbase[kc * 8 + 1];
      }
    }
    bf16x8 at0, at1;
    #pragma unroll
    for (int e = 0; e < 8; ++e) {
      at0[e] = (short)bfc(e < 4 ? tv[t][0][e] : tv[t][1][e - 4]);
      at1[e] = (short)bfc(e < 4 ? tv[t][2][e] : tv[t][3][e - 4]);
    }
    #pragma unroll
    for (int n = 0; n < 4; ++n) {
      f32x4 kT = (f32x4){0.f, 0.f, 0.f, 0.f};
      f32x4 vT = (f32x4){0.f, 0.f, 0.f, 0.f};
      kT = __builtin_amdgcn_mfma_f32_16x16x32_bf16(wf[WKF(n, 0) + lane], at0, kT, 0, 0, 0);
      kT = __builtin_amdgcn_mfma_f32_16x16x32_bf16(wf[WKF(n, 1) + lane], at1, kT, 0, 0, 0);
      vT = __builtin_amdgcn_mfma_f32_16x16x32_bf16(wf[WVF(n, 0) + lane], at0, vT, 0, 0, 0);
      vT = __builtin_amdgcn_mfma_f32_16x16x32_bf16(wf[WVF(n, 1) + lane], at1, vT, 0, 0, 0);
      float lg = qT[n][0] * kT[0] + qT[n][1] * kT[1] + qT[n][2] * kT[2] + qT[n][3] * kT[3];
      lg += __shfl_xor(lg, 16);
      lg += __shfl_xor(lg, 32);     // logit(pos=l15, head n), bcast over g
      const float w = __expf(lg + biasv[t]);
      ssum[n] += w;
      #pragma unroll
      for (int r = 0; r < 4; ++r) wvT[n][r] += w * vT[r];
    }
  }

  // ---- normalize + pack to bf16 pairs ----
  u32 pk[4][2];
  #pragma unroll
  for (int n = 0; n < 4; ++n) {
    const float inv = tmk / fmaxf(ssum[n], 1e-30f);
    pk[n][0] = (u32)bfc(wvT[n][0] * inv) | ((u32)bfc(wvT[n][1] * inv) << 16);
    pk[n][1] = (u32)bfc(wvT[n][2] * inv) | ((u32)bfc(wvT[n][3] * inv) << 16);
  }

  // ---- transpose WV[d][pos] -> A/B-frag WV[pos][hd] via 4-lane-group shfl ----
  // awv[kc] elem e: WV[pos=l15][hd=kc*32+g*8+e]; src lane=(l15, (g&1)*2+(e>>2)),
  // src reg pk[kc*2+(g>>1)][(e&3)>>1... pairs]: word w holds e=2w,2w+1.
  union { u32 w[4]; bf16x8 v; } awv[2];
  #pragma unroll
  for (int kc = 0; kc < 2; ++kc)
    #pragma unroll
    for (int w = 0; w < 4; ++w) {
      const int j = w & 1, hi = w >> 1;
      const int src = l15 + 16 * ((g & 1) * 2 + hi);
      const u32 t0 = __shfl(pk[kc * 2 + 0][j], src);
      const u32 t1 = __shfl(pk[kc * 2 + 1][j], src);
      awv[kc].w[w] = (g >> 1) ? t1 : t0;
    }

  // ---- GEMM4 (both operands in frag layout): OUT^T tile, then f32x4 store ----
  const f32x4* obase = reinterpret_cast<const f32x4*>(ob);
  f32x4* orow = reinterpret_cast<f32x4*>(out + (size_t)(p0 + l15) * 128);
  #pragma unroll
  for (int n8 = 0; n8 < 8; ++n8) {
    f32x4 acc = (f32x4){0.f, 0.f, 0.f, 0.f};
    acc = __builtin_amdgcn_mfma_f32_16x16x32_bf16(wf[WOF(n8, 0) + lane], awv[0].v, acc, 0, 0, 0);
    acc = __builtin_amdgcn_mfma_f32_16x16x32_bf16(wf[WOF(n8, 1) + lane], awv[1].v, acc, 0, 0, 0);
    const f32x4 obf = obase[n8 * 4 + g];    // ob[n8*16+g*4 .. +4)
    f32x4 res;
    #pragma unroll
    for (int r = 0; r < 4; ++r) res[r] = acc[r] + obf[r] * tmk;
    orow[n8 * 4 + g] = res;                 // out[p0+l15][n8*16+g*4 .. +4)
  }
}

extern "C" void kernel_launch(void* const* d_in, const int* in_sizes, int n_in,
                              void* d_out, int out_size, void* d_ws, size_t ws_size,
                              hipStream_t stream) {
  const float* qe  = (const float*)d_in[0];
  const float* tpr = (const float*)d_in[1];
  const float* tmk = (const float*)d_in[2];
  const float* wq  = (const float*)d_in[3];
  const float* wk  = (const float*)d_in[4];
  const float* wv  = (const float*)d_in[5];
  const float* wo  = (const float*)d_in[6];
  const float* ob  = (const float*)d_in[7];
  float* out = (float*)d_out;
  u16* wsf = (u16*)d_ws;

  prep_kernel<<<96, 256, 0, stream>>>(wq, wk, wv, wo, wsf);
  tpa_kernel<<<NTILES, 64, 0, stream>>>(qe, tpr, tmk, ob, wsf, out);
}

// Round 3
// 85.845 us; speedup vs baseline: 2.0539x; 2.0539x over previous
//
#include <hip/hip_runtime.h>
#include <hip/hip_bf16.h>

typedef __attribute__((ext_vector_type(8))) short bf16x8;
typedef __attribute__((ext_vector_type(4))) float f32x4;
typedef unsigned int u32;
typedef unsigned short u16;

#define NPOS 147456      // 384*384
#define NTILES 9216      // NPOS/16

__device__ inline u16 bfc(float f) {
  union { __hip_bfloat16 h; u16 s; } u;
  u.h = __float2bfloat16(f);
  return u.s;
}

// ---------------------------------------------------------------------------
// Prologue: bake bf16 weight fragments into ws, in exact MFMA lane layout.
// ws layout in u16 units:
//   wqf [0,8192)      : 16 frags (n*4+kc), frag = 64 lanes x 8 elems, Wq^T*0.25
//   wkf [8192,12288)  :  8 frags (n*2+kc), Wk^T
//   wvf [12288,16384) :  8 frags (n*2+kc), Wv^T
//   wof [16384,24576) : 16 frags (n8*2+kc), Wo^T
// Frag elem (lane,e): A[row=lane&15][k=(lane>>4)*8+e] of the 16x32 operand.
// ---------------------------------------------------------------------------
__global__ void prep_kernel(const float* __restrict__ wq, const float* __restrict__ wk,
                            const float* __restrict__ wv, const float* __restrict__ wo,
                            u16* __restrict__ wsf) {
  int gid = blockIdx.x * 256 + threadIdx.x;   // [0, 24576)
  int idx, which;
  if (gid < 8192)       { idx = gid;         which = 0; }
  else if (gid < 12288) { idx = gid - 8192;  which = 1; }
  else if (gid < 16384) { idx = gid - 12288; which = 2; }
  else                  { idx = gid - 16384; which = 3; }
  int fragid = idx >> 9, lane = (idx >> 3) & 63, e = idx & 7;
  int l15 = lane & 15, g = lane >> 4;
  float v;
  if (which == 0) {        // wq: [4][128][16], A[row=d][k=c]
    int n = fragid >> 2, kc = fragid & 3;
    int c = kc * 32 + g * 8 + e;
    v = wq[n * 2048 + c * 16 + l15] * 0.25f;   // fold D^-0.5
  } else if (which == 1) { // wk: [4][64][16], A[row=d][k=c]
    int n = fragid >> 1, kc = fragid & 1;
    int c = kc * 32 + g * 8 + e;
    v = wk[n * 1024 + c * 16 + l15];
  } else if (which == 2) { // wv
    int n = fragid >> 1, kc = fragid & 1;
    int c = kc * 32 + g * 8 + e;
    v = wv[n * 1024 + c * 16 + l15];
  } else {                 // wo: [4][16][128], A[row=cq-sub][k=hd]
    int n8 = fragid >> 1, kc = fragid & 1;
    int hd = kc * 32 + g * 8 + e;
    v = wo[(hd >> 4) * 2048 + (hd & 15) * 128 + n8 * 16 + l15];
  }
  wsf[gid] = bfc(v);
}

// frag-unit (bf16x8) index bases in ws
#define WQF(n, kc)  ((      (n) * 4 + (kc)) * 64)
#define WKF(n, kc)  (1024 + ((n) * 2 + (kc)) * 64)
#define WVF(n, kc)  (1536 + ((n) * 2 + (kc)) * 64)
#define WOF(n8, kc) (2048 + ((n8) * 2 + (kc)) * 64)

// ---------------------------------------------------------------------------
// Main: 1 wave per 16-position tile. No LDS, no __syncthreads, no VGPR cap.
// Template rows double-buffered (2 live instead of 4) to keep regs ~<=140.
// ---------------------------------------------------------------------------
__global__ __launch_bounds__(64) void tpa_kernel(
    const float* __restrict__ qe, const float* __restrict__ tpr,
    const float* __restrict__ tmk_p, const float* __restrict__ ob,
    const u16* __restrict__ wsf, float* __restrict__ out)
{
  const int lane = threadIdx.x;
  const int l15 = lane & 15, g = lane >> 4;
  const int p0 = blockIdx.x * 16;
  const bf16x8* __restrict__ wf = reinterpret_cast<const bf16x8*>(wsf);

  // ---- issue q loads + template rows 0,1 (double buffer) ----
  const f32x4* qbase = reinterpret_cast<const f32x4*>(qe) + (p0 + l15) * 32 + g * 2;
  f32x4 qv[8];
  #pragma unroll
  for (int kc = 0; kc < 4; ++kc) {
    qv[kc * 2 + 0] = qbase[kc * 8 + 0];
    qv[kc * 2 + 1] = qbase[kc * 8 + 1];
  }

#define LOADT(buf, t)                                                          \
  {                                                                            \
    const f32x4* tb = reinterpret_cast<const f32x4*>(tpr) +                    \
                      ((size_t)(t) * NPOS + p0 + l15) * 16 + g * 2;            \
    buf[0] = tb[0]; buf[1] = tb[1]; buf[2] = tb[8]; buf[3] = tb[9];            \
  }

  f32x4 tva[4], tvb[4];
  LOADT(tva, 0)
  LOADT(tvb, 1)

  const float m0 = tmk_p[0], m1 = tmk_p[1], m2 = tmk_p[2], m3 = tmk_p[3];
  const float biasv[4] = {65504.0f * (m0 - 1.0f), 65504.0f * (m1 - 1.0f),
                          65504.0f * (m2 - 1.0f), 65504.0f * (m3 - 1.0f)};
  const float tmk = (m0 + m1 + m2 + m3 > 0.0f) ? 1.0f : 0.0f;

  // ---- GEMM1 (swapped): qT[n] = Q^T tile, lane = [d=g*4+r][pos=l15] ----
  f32x4 qT[4];
  #pragma unroll
  for (int n = 0; n < 4; ++n) qT[n] = (f32x4){0.f, 0.f, 0.f, 0.f};
  #pragma unroll
  for (int kc = 0; kc < 4; ++kc) {
    bf16x8 aq;
    #pragma unroll
    for (int e = 0; e < 8; ++e)
      aq[e] = (short)bfc(e < 4 ? qv[kc * 2 + 0][e] : qv[kc * 2 + 1][e - 4]);
    #pragma unroll
    for (int n = 0; n < 4; ++n)
      qT[n] = __builtin_amdgcn_mfma_f32_16x16x32_bf16(wf[WQF(n, kc) + lane], aq, qT[n], 0, 0, 0);
  }

  // ---- template loop (explicitly unrolled, 2-deep prefetch) ----
  float ssum[4] = {0.f, 0.f, 0.f, 0.f};
  f32x4 wvT[4];
  #pragma unroll
  for (int n = 0; n < 4; ++n) wvT[n] = (f32x4){0.f, 0.f, 0.f, 0.f};

#define CVT2(at0, at1, buf)                                                    \
  {                                                                            \
    _Pragma("unroll")                                                          \
    for (int e = 0; e < 8; ++e) {                                              \
      at0[e] = (short)bfc(e < 4 ? buf[0][e] : buf[1][e - 4]);                  \
      at1[e] = (short)bfc(e < 4 ? buf[2][e] : buf[3][e - 4]);                  \
    }                                                                          \
  }

#define TSTEP(at0, at1, bias)                                                  \
  {                                                                            \
    _Pragma("unroll")                                                          \
    for (int n = 0; n < 4; ++n) {                                              \
      f32x4 kT = (f32x4){0.f, 0.f, 0.f, 0.f};                                  \
      f32x4 vT = (f32x4){0.f, 0.f, 0.f, 0.f};                                  \
      kT = __builtin_amdgcn_mfma_f32_16x16x32_bf16(wf[WKF(n, 0) + lane], at0, kT, 0, 0, 0); \
      kT = __builtin_amdgcn_mfma_f32_16x16x32_bf16(wf[WKF(n, 1) + lane], at1, kT, 0, 0, 0); \
      vT = __builtin_amdgcn_mfma_f32_16x16x32_bf16(wf[WVF(n, 0) + lane], at0, vT, 0, 0, 0); \
      vT = __builtin_amdgcn_mfma_f32_16x16x32_bf16(wf[WVF(n, 1) + lane], at1, vT, 0, 0, 0); \
      float lg = qT[n][0] * kT[0] + qT[n][1] * kT[1] + qT[n][2] * kT[2] + qT[n][3] * kT[3]; \
      lg += __shfl_xor(lg, 16);                                                \
      lg += __shfl_xor(lg, 32);                                                \
      const float w = __expf(lg + (bias));                                     \
      ssum[n] += w;                                                            \
      _Pragma("unroll")                                                        \
      for (int r = 0; r < 4; ++r) wvT[n][r] += w * vT[r];                      \
    }                                                                          \
  }

  {
    bf16x8 at0, at1;
    CVT2(at0, at1, tva)          // frees tva's f32 regs
    LOADT(tva, 2)                // prefetch t=2 into freed buffer
    TSTEP(at0, at1, biasv[0])
  }
  {
    bf16x8 at0, at1;
    CVT2(at0, at1, tvb)
    LOADT(tvb, 3)
    TSTEP(at0, at1, biasv[1])
  }
  {
    bf16x8 at0, at1;
    CVT2(at0, at1, tva)
    TSTEP(at0, at1, biasv[2])
  }
  {
    bf16x8 at0, at1;
    CVT2(at0, at1, tvb)
    TSTEP(at0, at1, biasv[3])
  }

  // ---- normalize + pack to bf16 pairs ----
  u32 pk[4][2];
  #pragma unroll
  for (int n = 0; n < 4; ++n) {
    const float inv = tmk / fmaxf(ssum[n], 1e-30f);
    pk[n][0] = (u32)bfc(wvT[n][0] * inv) | ((u32)bfc(wvT[n][1] * inv) << 16);
    pk[n][1] = (u32)bfc(wvT[n][2] * inv) | ((u32)bfc(wvT[n][3] * inv) << 16);
  }

  // ---- transpose WV[d][pos] -> frag WV[pos][hd] via shfl ----
  union { u32 w[4]; bf16x8 v; } awv[2];
  #pragma unroll
  for (int kc = 0; kc < 2; ++kc)
    #pragma unroll
    for (int w = 0; w < 4; ++w) {
      const int j = w & 1, hi = w >> 1;
      const int src = l15 + 16 * ((g & 1) * 2 + hi);
      const u32 t0 = __shfl(pk[kc * 2 + 0][j], src);
      const u32 t1 = __shfl(pk[kc * 2 + 1][j], src);
      awv[kc].w[w] = (g >> 1) ? t1 : t0;
    }

  // ---- GEMM4 (both operands in frag layout) + f32x4 store ----
  const f32x4* obase = reinterpret_cast<const f32x4*>(ob);
  f32x4* orow = reinterpret_cast<f32x4*>(out + (size_t)(p0 + l15) * 128);
  #pragma unroll
  for (int n8 = 0; n8 < 8; ++n8) {
    f32x4 acc = (f32x4){0.f, 0.f, 0.f, 0.f};
    acc = __builtin_amdgcn_mfma_f32_16x16x32_bf16(wf[WOF(n8, 0) + lane], awv[0].v, acc, 0, 0, 0);
    acc = __builtin_amdgcn_mfma_f32_16x16x32_bf16(wf[WOF(n8, 1) + lane], awv[1].v, acc, 0, 0, 0);
    const f32x4 obf = obase[n8 * 4 + g];    // ob[n8*16+g*4 .. +4)
    f32x4 res;
    #pragma unroll
    for (int r = 0; r < 4; ++r) res[r] = acc[r] + obf[r] * tmk;
    orow[n8 * 4 + g] = res;                 // out[p0+l15][n8*16+g*4 .. +4)
  }
}

extern "C" void kernel_launch(void* const* d_in, const int* in_sizes, int n_in,
                              void* d_out, int out_size, void* d_ws, size_t ws_size,
                              hipStream_t stream) {
  const float* qe  = (const float*)d_in[0];
  const float* tpr = (const float*)d_in[1];
  const float* tmk = (const float*)d_in[2];
  const float* wq  = (const float*)d_in[3];
  const float* wk  = (const float*)d_in[4];
  const float* wv  = (const float*)d_in[5];
  const float* wo  = (const float*)d_in[6];
  const float* ob  = (const float*)d_in[7];
  float* out = (float*)d_out;
  u16* wsf = (u16*)d_ws;

  prep_kernel<<<96, 256, 0, stream>>>(wq, wk, wv, wo, wsf);
  tpa_kernel<<<NTILES, 64, 0, stream>>>(qe, tpr, tmk, ob, wsf, out);
}